// Round 2
// baseline (644.288 us; speedup 1.0000x reference)
//
#include <hip/hip_runtime.h>
#include <hip/hip_bf16.h>

#define NB 128
#define NL 32
#define NJ 31
#define NC 256
#define NCJ 128
#define LNEPS 1e-5f

// flat link layout: (B, L, C, 4, 4) -> ((b*NL + l)*NC + c)*16 + x*4 + z

__device__ __forceinline__ void fma4(float4& a, float s, const float4& v) {
  a.x = fmaf(s, v.x, a.x);
  a.y = fmaf(s, v.y, a.y);
  a.z = fmaf(s, v.z, a.z);
  a.w = fmaf(s, v.w, a.w);
}

// 256-thread (4-wave) block reduction of (s, s2)
__device__ __forceinline__ void block_reduce2(float& s, float& s2, float* red, int t) {
  #pragma unroll
  for (int off = 32; off > 0; off >>= 1) {
    s  += __shfl_down(s, off);
    s2 += __shfl_down(s2, off);
  }
  int wid = t >> 6;
  if ((t & 63) == 0) { red[wid] = s; red[4 + wid] = s2; }
  __syncthreads();
  if (t == 0) {
    red[0] = red[0] + red[1] + red[2] + red[3];
    red[4] = red[4] + red[5] + red[6] + red[7];
  }
  __syncthreads();
  s = red[0]; s2 = red[4];
}

__global__ __launch_bounds__(256) void rodrigues_fused(
    const float* __restrict__ link,   // (B,L,C,16)
    const float* __restrict__ jf,     // (B,J,CJ)
    const float* __restrict__ W,      // (J,3,C,C)
    const float* __restrict__ Kw,     // (J,16,CJ)
    const float* __restrict__ Kb,     // (J,16)
    const float* __restrict__ gam,    // (L, C*16)
    const float* __restrict__ bet,    // (L, C*16)
    const int* __restrict__ parent_idx,
    const int* __restrict__ child_idx,
    float* __restrict__ out)          // (B,L,C,16)
{
  __shared__ float Bop[3 * NC * 16];  // 48 KB: [Fp ; K*Fp ; K2*Fp], row = (s,c), 16 xz each
  __shared__ float jfs[NCJ];
  __shared__ float Ks[16];
  __shared__ float K2s[16];
  __shared__ float red[8];

  const int bx = blockIdx.x;
  const int t  = threadIdx.x;

  if (bx >= NJ * NB) {
    // ---- root block: out[b,0] = LN(link[b,0]) with gamma/beta row 0 ----
    const int b = bx - NJ * NB;
    const float4* src4 = reinterpret_cast<const float4*>(link + (size_t)b * NL * (NC * 16));
    float4 v[4];
    float s = 0.f, s2 = 0.f;
    #pragma unroll
    for (int i = 0; i < 4; ++i) {
      v[i] = src4[t + i * 256];
      s  += v[i].x + v[i].y + v[i].z + v[i].w;
      s2 += v[i].x * v[i].x + v[i].y * v[i].y + v[i].z * v[i].z + v[i].w * v[i].w;
    }
    block_reduce2(s, s2, red, t);
    const float mean = s * (1.f / 4096.f);
    const float var  = s2 * (1.f / 4096.f) - mean * mean;
    const float rstd = rsqrtf(var + LNEPS);
    const float4* g4 = reinterpret_cast<const float4*>(gam);
    const float4* b4 = reinterpret_cast<const float4*>(bet);
    float4* o4 = reinterpret_cast<float4*>(out + (size_t)b * NL * (NC * 16));
    #pragma unroll
    for (int i = 0; i < 4; ++i) {
      const int f = t + i * 256;
      float4 g = g4[f], be = b4[f], o;
      o.x = (v[i].x - mean) * rstd * g.x + be.x;
      o.y = (v[i].y - mean) * rstd * g.y + be.y;
      o.z = (v[i].z - mean) * rstd * g.z + be.z;
      o.w = (v[i].w - mean) * rstd * g.w + be.w;
      o4[f] = o;
    }
    return;
  }

  const int j = bx / NB;   // j-major: consecutive blocks share W[j] in L2
  const int b = bx % NB;
  const int pj = parent_idx[j];
  const int cj = child_idx[j];

  // ---- stage Fp into Bop[s=0] (coalesced), joint feats into LDS ----
  {
    float4* Bop4 = reinterpret_cast<float4*>(Bop);
    const float4* lp4 = reinterpret_cast<const float4*>(link + ((size_t)b * NL + pj) * (NC * 16));
    #pragma unroll
    for (int i = 0; i < 4; ++i) Bop4[t + i * 256] = lp4[t + i * 256];
    if (t < NCJ) jfs[t] = jf[((size_t)b * NJ + j) * NCJ + t];
  }
  __syncthreads();

  // ---- Kmat = jf @ Kw^T + Kb  (16 dots of length 128), then K2 = K@K ----
  if (t < 16) {
    const float* kwr = Kw + ((size_t)j * 16 + t) * NCJ;
    float acc = Kb[j * 16 + t];
    for (int q = 0; q < NCJ; ++q) acc = fmaf(jfs[q], kwr[q], acc);
    Ks[t] = acc;
  }
  __syncthreads();
  if (t < 16) {
    const int x = t >> 2, y = t & 3;
    float a = 0.f;
    #pragma unroll
    for (int m = 0; m < 4; ++m) a = fmaf(Ks[x * 4 + m], Ks[m * 4 + y], a);
    K2s[t] = a;
  }
  __syncthreads();

  // ---- build Bop[s=1] = K*Fp, Bop[s=2] = K2*Fp (per channel 4x4 left-mult) ----
  {
    const int c = t;
    float f[16];
    #pragma unroll
    for (int e = 0; e < 16; ++e) f[e] = Bop[c * 16 + e];
    #pragma unroll
    for (int x = 0; x < 4; ++x) {
      #pragma unroll
      for (int z = 0; z < 4; ++z) {
        float a1 = 0.f, a2 = 0.f;
        #pragma unroll
        for (int y = 0; y < 4; ++y) {
          a1 = fmaf(Ks[x * 4 + y],  f[y * 4 + z], a1);
          a2 = fmaf(K2s[x * 4 + y], f[y * 4 + z], a2);
        }
        Bop[(NC + c) * 16 + x * 4 + z]     = a1;
        Bop[(2 * NC + c) * 16 + x * 4 + z] = a2;
      }
    }
  }
  __syncthreads();

  // ---- GEMM: F_trans[d, xz] = sum_{s,c} W[j,s,d,c] * Bop[(s,c), xz] ----
  // thread tile: 4 d rows x 4 xz (x = xzg fixed, z = 0..3)
  const int xzg = t & 3;
  const int dg  = t >> 2;
  const int d0  = dg * 4;

  float4 acc[4];
  acc[0] = acc[1] = acc[2] = acc[3] = make_float4(0.f, 0.f, 0.f, 0.f);

  const float* Wj = W + (size_t)j * 3 * NC * NC;
  for (int s = 0; s < 3; ++s) {
    const float4* wr0 = reinterpret_cast<const float4*>(Wj + ((size_t)s * NC + d0 + 0) * NC);
    const float4* wr1 = reinterpret_cast<const float4*>(Wj + ((size_t)s * NC + d0 + 1) * NC);
    const float4* wr2 = reinterpret_cast<const float4*>(Wj + ((size_t)s * NC + d0 + 2) * NC);
    const float4* wr3 = reinterpret_cast<const float4*>(Wj + ((size_t)s * NC + d0 + 3) * NC);
    const float4* bq = reinterpret_cast<const float4*>(Bop + s * NC * 16) + xzg;
    #pragma unroll 2
    for (int c4 = 0; c4 < NC / 4; ++c4) {
      const float4 w0 = wr0[c4];
      const float4 w1 = wr1[c4];
      const float4 w2 = wr2[c4];
      const float4 w3 = wr3[c4];
      const float4 b0 = bq[(4 * c4 + 0) * 4];
      const float4 b1 = bq[(4 * c4 + 1) * 4];
      const float4 b2 = bq[(4 * c4 + 2) * 4];
      const float4 b3 = bq[(4 * c4 + 3) * 4];
      fma4(acc[0], w0.x, b0); fma4(acc[0], w0.y, b1); fma4(acc[0], w0.z, b2); fma4(acc[0], w0.w, b3);
      fma4(acc[1], w1.x, b0); fma4(acc[1], w1.y, b1); fma4(acc[1], w1.z, b2); fma4(acc[1], w1.w, b3);
      fma4(acc[2], w2.x, b0); fma4(acc[2], w2.y, b1); fma4(acc[2], w2.z, b2); fma4(acc[2], w2.w, b3);
      fma4(acc[3], w3.x, b0); fma4(acc[3], w3.y, b1); fma4(acc[3], w3.z, b2); fma4(acc[3], w3.w, b3);
    }
  }

  // ---- epilogue: comb = Fc + F_trans, LayerNorm over 4096, write out[b, cj] ----
  const float* linkc = link + ((size_t)b * NL + cj) * (NC * 16);
  float vals[16];
  float s = 0.f, s2 = 0.f;
  #pragma unroll
  for (int dd = 0; dd < 4; ++dd) {
    const float4 fc = *reinterpret_cast<const float4*>(linkc + (d0 + dd) * 16 + xzg * 4);
    float4 vv = acc[dd];
    vv.x += fc.x; vv.y += fc.y; vv.z += fc.z; vv.w += fc.w;
    vals[dd * 4 + 0] = vv.x; vals[dd * 4 + 1] = vv.y;
    vals[dd * 4 + 2] = vv.z; vals[dd * 4 + 3] = vv.w;
    s  += vv.x + vv.y + vv.z + vv.w;
    s2 += vv.x * vv.x + vv.y * vv.y + vv.z * vv.z + vv.w * vv.w;
  }
  block_reduce2(s, s2, red, t);
  const float mean = s * (1.f / 4096.f);
  const float var  = s2 * (1.f / 4096.f) - mean * mean;
  const float rstd = rsqrtf(var + LNEPS);

  const float* g  = gam + (size_t)cj * (NC * 16);
  const float* be = bet + (size_t)cj * (NC * 16);
  float* op = out + ((size_t)b * NL + cj) * (NC * 16);
  #pragma unroll
  for (int dd = 0; dd < 4; ++dd) {
    const int f = (d0 + dd) * 16 + xzg * 4;
    const float4 gg = *reinterpret_cast<const float4*>(g + f);
    const float4 bb = *reinterpret_cast<const float4*>(be + f);
    float4 o;
    o.x = (vals[dd * 4 + 0] - mean) * rstd * gg.x + bb.x;
    o.y = (vals[dd * 4 + 1] - mean) * rstd * gg.y + bb.y;
    o.z = (vals[dd * 4 + 2] - mean) * rstd * gg.z + bb.z;
    o.w = (vals[dd * 4 + 3] - mean) * rstd * gg.w + bb.w;
    *reinterpret_cast<float4*>(op + f) = o;
  }
}

extern "C" void kernel_launch(void* const* d_in, const int* in_sizes, int n_in,
                              void* d_out, int out_size, void* d_ws, size_t ws_size,
                              hipStream_t stream) {
  const float* link = (const float*)d_in[0];
  const float* jf   = (const float*)d_in[1];
  const float* W    = (const float*)d_in[2];
  const float* Kw   = (const float*)d_in[3];
  const float* Kb   = (const float*)d_in[4];
  const float* gam  = (const float*)d_in[5];
  const float* bet  = (const float*)d_in[6];
  const int* pidx   = (const int*)d_in[7];
  const int* cidx   = (const int*)d_in[8];
  float* out = (float*)d_out;

  dim3 grid(NJ * NB + NB);  // 3968 child blocks (j-major) + 128 root LN blocks
  dim3 block(256);
  hipLaunchKernelGGL(rodrigues_fused, grid, block, 0, stream,
                     link, jf, W, Kw, Kb, gam, bet, pidx, cidx, out);
}

// Round 3
// 323.319 us; speedup vs baseline: 1.9927x; 1.9927x over previous
//
#include <hip/hip_runtime.h>
#include <hip/hip_bf16.h>
#include <stdint.h>

#define NB 128
#define NL 32
#define NJ 31
#define NC 256
#define NCJ 128
#define LNEPS 1e-5f

typedef unsigned short u16;
typedef unsigned int u32;

using bf16x8 = __attribute__((ext_vector_type(8))) short;  // 8 bf16 in 4 VGPRs
using f32x4  = __attribute__((ext_vector_type(4))) float;  // MFMA accumulator

__device__ __forceinline__ u16 f2bf(float v) {
  __hip_bfloat16 h = __float2bfloat16(v);
  return __builtin_bit_cast(u16, h);
}
__device__ __forceinline__ float bf2f(u16 b) {
  __hip_bfloat16 h = __builtin_bit_cast(__hip_bfloat16, b);
  return __bfloat162float(h);
}

// 256-thread (4-wave) block reduction of (s, s2)
__device__ __forceinline__ void block_reduce2(float& s, float& s2, float* red, int t) {
  #pragma unroll
  for (int off = 32; off > 0; off >>= 1) {
    s  += __shfl_down(s, off);
    s2 += __shfl_down(s2, off);
  }
  int wid = t >> 6;
  if ((t & 63) == 0) { red[wid] = s; red[4 + wid] = s2; }
  __syncthreads();
  if (t == 0) {
    red[0] = red[0] + red[1] + red[2] + red[3];
    red[4] = red[4] + red[5] + red[6] + red[7];
  }
  __syncthreads();
  s = red[0]; s2 = red[4];
}

// ---- prepass: W fp32 -> bf16 in d_ws (12.19 MB) ----
__global__ __launch_bounds__(256) void convert_w(const float* __restrict__ W,
                                                 u16* __restrict__ Wb, int n) {
  const int i = (blockIdx.x * 256 + threadIdx.x) * 8;
  if (i + 8 > n) return;
  const float4 a = *reinterpret_cast<const float4*>(W + i);
  const float4 b = *reinterpret_cast<const float4*>(W + i + 4);
  uint4 o;
  o.x = (u32)f2bf(a.x) | ((u32)f2bf(a.y) << 16);
  o.y = (u32)f2bf(a.z) | ((u32)f2bf(a.w) << 16);
  o.z = (u32)f2bf(b.x) | ((u32)f2bf(b.y) << 16);
  o.w = (u32)f2bf(b.z) | ((u32)f2bf(b.w) << 16);
  *reinterpret_cast<uint4*>(Wb + i) = o;
}

// LDS B-operand layout: [n=16][k=768] bf16, row pitch 1536 B,
// byte addr = (n*1536 + k*2) ^ ((n&7)<<4)   (T2 swizzle, write==read)
template<bool USE_WS>
__global__ __launch_bounds__(256, 3) void rodrigues_mfma(
    const float* __restrict__ link,   // (B,L,C,16)
    const float* __restrict__ jf,     // (B,J,CJ)
    const float* __restrict__ W,      // (J,3,C,C) fp32
    const u16*   __restrict__ Wb,     // (J,3,C,C) bf16 (ws) or null
    const float* __restrict__ Kw,     // (J,16,CJ)
    const float* __restrict__ Kb,     // (J,16)
    const float* __restrict__ gam,    // (L, C*16)
    const float* __restrict__ bet,    // (L, C*16)
    const int* __restrict__ parent_idx,
    const int* __restrict__ child_idx,
    float* __restrict__ out)          // (B,L,C,16)
{
  __shared__ __align__(16) u16 Bh[16 * 768];  // 24 KB hi
  __shared__ __align__(16) u16 Bl[16 * 768];  // 24 KB lo
  __shared__ float jfs[NCJ];
  __shared__ float Ks[16], K2s[16];
  __shared__ float red[8];

  const int bx = blockIdx.x;
  const int t  = threadIdx.x;

  if (bx >= NJ * NB) {
    // ---- root block: out[b,0] = LN(link[b,0]), gamma/beta row 0 ----
    const int b = bx - NJ * NB;
    const float4* src4 = reinterpret_cast<const float4*>(link + (size_t)b * NL * 4096);
    float4 v[4];
    float s = 0.f, s2 = 0.f;
    #pragma unroll
    for (int i = 0; i < 4; ++i) {
      v[i] = src4[t + i * 256];
      s  += v[i].x + v[i].y + v[i].z + v[i].w;
      s2 += v[i].x * v[i].x + v[i].y * v[i].y + v[i].z * v[i].z + v[i].w * v[i].w;
    }
    block_reduce2(s, s2, red, t);
    const float mean = s * (1.f / 4096.f);
    const float var  = s2 * (1.f / 4096.f) - mean * mean;
    const float rstd = rsqrtf(var + LNEPS);
    const float4* g4 = reinterpret_cast<const float4*>(gam);
    const float4* b4 = reinterpret_cast<const float4*>(bet);
    float4* o4 = reinterpret_cast<float4*>(out + (size_t)b * NL * 4096);
    #pragma unroll
    for (int i = 0; i < 4; ++i) {
      const int f = t + i * 256;
      float4 g = g4[f], be = b4[f], o;
      o.x = (v[i].x - mean) * rstd * g.x + be.x;
      o.y = (v[i].y - mean) * rstd * g.y + be.y;
      o.z = (v[i].z - mean) * rstd * g.z + be.z;
      o.w = (v[i].w - mean) * rstd * g.w + be.w;
      o4[f] = o;
    }
    return;
  }

  const int j = bx / NB;   // j-major: blocks sharing W[j] cluster in time
  const int b = bx % NB;
  const int pj = parent_idx[j];
  const int cj = child_idx[j];

  // ---- stage joint feats ----
  if (t < NCJ) jfs[t] = jf[((size_t)b * NJ + j) * NCJ + t];
  __syncthreads();

  // ---- K = jf @ Kw^T + Kb ----
  if (t < 16) {
    const float* kwr = Kw + ((size_t)j * 16 + t) * NCJ;
    float acc = Kb[j * 16 + t];
    for (int q = 0; q < NCJ; ++q) acc = fmaf(jfs[q], kwr[q], acc);
    Ks[t] = acc;
  }
  __syncthreads();
  if (t < 16) {
    const int x = t >> 2, y = t & 3;
    float a = 0.f;
    #pragma unroll
    for (int m = 0; m < 4; ++m) a = fmaf(Ks[x * 4 + m], Ks[m * 4 + y], a);
    K2s[t] = a;
  }
  __syncthreads();

  // ---- build B operand: rows k=(s,c): s0=Fp, s1=K*Fp, s2=K2*Fp; bf16 hi/lo split ----
  {
    const int c = t;
    const float* fp = link + ((size_t)b * NL + pj) * 4096 + c * 16;
    float f[16];
    #pragma unroll
    for (int i = 0; i < 4; ++i) {
      const float4 v = reinterpret_cast<const float4*>(fp)[i];
      f[4 * i + 0] = v.x; f[4 * i + 1] = v.y; f[4 * i + 2] = v.z; f[4 * i + 3] = v.w;
    }
    float kf[16], k2f[16];
    #pragma unroll
    for (int x = 0; x < 4; ++x)
      #pragma unroll
      for (int z = 0; z < 4; ++z) {
        float a1 = 0.f, a2 = 0.f;
        #pragma unroll
        for (int y = 0; y < 4; ++y) {
          a1 = fmaf(Ks[x * 4 + y],  f[y * 4 + z], a1);
          a2 = fmaf(K2s[x * 4 + y], f[y * 4 + z], a2);
        }
        kf[x * 4 + z] = a1;
        k2f[x * 4 + z] = a2;
      }
    char* bhB = reinterpret_cast<char*>(Bh);
    char* blB = reinterpret_cast<char*>(Bl);
    #pragma unroll
    for (int xz = 0; xz < 16; ++xz) {
      const int swz  = (xz & 7) << 4;
      const int rowb = xz * 1536;
      #pragma unroll
      for (int s = 0; s < 3; ++s) {
        const float v = (s == 0) ? f[xz] : (s == 1) ? kf[xz] : k2f[xz];
        const u16 h  = f2bf(v);
        const u16 lo = f2bf(v - bf2f(h));
        const int byte = (rowb + s * 512 + c * 2) ^ swz;
        *reinterpret_cast<u16*>(bhB + byte) = h;
        *reinterpret_cast<u16*>(blB + byte) = lo;
      }
    }
  }
  __syncthreads();

  // ---- MFMA GEMM: D[d, xz] = sum_k W[j,k(d-row)] * B[k][xz], K=768, 24 steps ----
  const int lane = t & 63;
  const int wv   = t >> 6;        // wave owns M-strip [wv*64, wv*64+64)
  const int rw   = lane & 15;     // A-row (d low), B-col (xz), D-col
  const int kg   = lane >> 4;     // k-group (8 consecutive k each)

  f32x4 acc[4];
  #pragma unroll
  for (int m = 0; m < 4; ++m) acc[m] = (f32x4){0.f, 0.f, 0.f, 0.f};

  const char* bhB = reinterpret_cast<const char*>(Bh);
  const char* blB = reinterpret_cast<const char*>(Bl);
  const int bframe = rw * 1536 + kg * 16;
  const int bswz   = (rw & 7) << 4;
  const int dbase  = wv * 64 + rw;

  for (int kt = 0; kt < 24; ++kt) {
    const int s  = kt >> 3;
    const int c0 = (kt & 7) * 32 + kg * 8;
    bf16x8 af[4];
    if (USE_WS) {
      const u16* wj = Wb + (size_t)j * 3 * 65536;
      #pragma unroll
      for (int m = 0; m < 4; ++m) {
        const int d = dbase + m * 16;
        af[m] = *reinterpret_cast<const bf16x8*>(wj + (size_t)(s * 256 + d) * 256 + c0);
      }
    } else {
      const float* wj = W + (size_t)j * 3 * 65536;
      #pragma unroll
      for (int m = 0; m < 4; ++m) {
        const int d = dbase + m * 16;
        const float* p = wj + (size_t)(s * 256 + d) * 256 + c0;
        const float4 w0 = reinterpret_cast<const float4*>(p)[0];
        const float4 w1 = reinterpret_cast<const float4*>(p)[1];
        bf16x8 fr;
        fr[0] = (short)f2bf(w0.x); fr[1] = (short)f2bf(w0.y);
        fr[2] = (short)f2bf(w0.z); fr[3] = (short)f2bf(w0.w);
        fr[4] = (short)f2bf(w1.x); fr[5] = (short)f2bf(w1.y);
        fr[6] = (short)f2bf(w1.z); fr[7] = (short)f2bf(w1.w);
        af[m] = fr;
      }
    }
    const int bo = (bframe + kt * 64) ^ bswz;
    const bf16x8 bh = *reinterpret_cast<const bf16x8*>(bhB + bo);
    const bf16x8 bl = *reinterpret_cast<const bf16x8*>(blB + bo);
    #pragma unroll
    for (int m = 0; m < 4; ++m)
      acc[m] = __builtin_amdgcn_mfma_f32_16x16x32_bf16(af[m], bh, acc[m], 0, 0, 0);
    #pragma unroll
    for (int m = 0; m < 4; ++m)
      acc[m] = __builtin_amdgcn_mfma_f32_16x16x32_bf16(af[m], bl, acc[m], 0, 0, 0);
  }

  // ---- epilogue: comb = Fc + D, LayerNorm over 4096, write out[b, cj] ----
  // D element (m, r): row d = wv*64 + m*16 + kg*4 + r, col xz = rw
  const float* linkc = link + ((size_t)b * NL + cj) * 4096;
  float vals[16];
  float s = 0.f, s2 = 0.f;
  #pragma unroll
  for (int m = 0; m < 4; ++m) {
    #pragma unroll
    for (int r = 0; r < 4; ++r) {
      const int d = wv * 64 + m * 16 + kg * 4 + r;
      const float v = acc[m][r] + linkc[d * 16 + rw];
      vals[m * 4 + r] = v;
      s += v; s2 += v * v;
    }
  }
  block_reduce2(s, s2, red, t);
  const float mean = s * (1.f / 4096.f);
  const float var  = s2 * (1.f / 4096.f) - mean * mean;
  const float rstd = rsqrtf(var + LNEPS);

  const float* g  = gam + (size_t)cj * 4096;
  const float* be = bet + (size_t)cj * 4096;
  float* op = out + ((size_t)b * NL + cj) * 4096;
  #pragma unroll
  for (int m = 0; m < 4; ++m) {
    #pragma unroll
    for (int r = 0; r < 4; ++r) {
      const int d = wv * 64 + m * 16 + kg * 4 + r;
      const int e = d * 16 + rw;
      op[e] = (vals[m * 4 + r] - mean) * rstd * g[e] + be[e];
    }
  }
}

extern "C" void kernel_launch(void* const* d_in, const int* in_sizes, int n_in,
                              void* d_out, int out_size, void* d_ws, size_t ws_size,
                              hipStream_t stream) {
  const float* link = (const float*)d_in[0];
  const float* jf   = (const float*)d_in[1];
  const float* W    = (const float*)d_in[2];
  const float* Kw   = (const float*)d_in[3];
  const float* Kb   = (const float*)d_in[4];
  const float* gam  = (const float*)d_in[5];
  const float* bet  = (const float*)d_in[6];
  const int* pidx   = (const int*)d_in[7];
  const int* cidx   = (const int*)d_in[8];
  float* out = (float*)d_out;

  const int W_ELEMS = NJ * 3 * NC * NC;                 // 6,094,848
  const size_t WB_BYTES = (size_t)W_ELEMS * sizeof(u16); // 12,189,696
  const bool use_ws = (d_ws != nullptr) && (ws_size >= WB_BYTES);

  dim3 grid(NJ * NB + NB);  // 3968 child blocks + 128 root blocks
  dim3 block(256);

  if (use_ws) {
    u16* Wb = (u16*)d_ws;
    dim3 pgrid(W_ELEMS / (256 * 8));  // 2976, exact
    hipLaunchKernelGGL(convert_w, pgrid, block, 0, stream, W, Wb, W_ELEMS);
    hipLaunchKernelGGL((rodrigues_mfma<true>), grid, block, 0, stream,
                       link, jf, W, (const u16*)Wb, Kw, Kb, gam, bet, pidx, cidx, out);
  } else {
    hipLaunchKernelGGL((rodrigues_mfma<false>), grid, block, 0, stream,
                       link, jf, W, (const u16*)nullptr, Kw, Kb, gam, bet, pidx, cidx, out);
  }
}